// Round 1
// baseline (53.334 us; speedup 1.0000x reference)
//
#include <hip/hip_runtime.h>
#include <math.h>

#define EPS 1e-8f

// Problem shape (fixed by setup_inputs)
constexpr int B = 8, H = 16, K = 2048, D = 128;
constexpr int BH = B * H;
constexpr int SPLIT = 16;                    // K-chunks per (b,h)
constexpr int ROWS_PER_CHUNK = K / SPLIT;    // 128
constexpr int WAVES = 4;                     // 256 threads/block
// out layout: [BH*K*D] (out) then [BH*K] (p_attn)
constexpr size_t P_OFF = (size_t)BH * K * D;

__global__ __launch_bounds__(256) void cosattn_kernel(
    const float* __restrict__ q,      // [BH, D]
    const float* __restrict__ key,    // [BH, K, D]
    const float* __restrict__ value,  // [BH, K, D]
    const int*   __restrict__ mask,   // [B, K]
    float* __restrict__ out)          // [BH*K*D] ++ [BH*K]
{
    const int tid  = threadIdx.x;
    const int lane = tid & 63;
    const int half = lane >> 5;       // which row of the pair this half-wave owns
    const int l32  = lane & 31;       // lane within 32-lane row group
    const int wave = tid >> 6;

    const int bh    = blockIdx.x / SPLIT;
    const int chunk = blockIdx.x % SPLIT;
    const int b     = bh / H;

    // Per-lane query fragment: q[l32*4 .. l32*4+3] (both halves identical)
    const float4 qv = *reinterpret_cast<const float4*>(q + (size_t)bh * D + l32 * 4);
    float qsq = qv.x*qv.x + qv.y*qv.y + qv.z*qv.z + qv.w*qv.w;
    #pragma unroll
    for (int s = 16; s >= 1; s >>= 1)
        qsq += __shfl_xor(qsq, s, 64);   // masks <32: stays inside each half
    const float qn = fmaxf(sqrtf(qsq), EPS);

    const int row0 = chunk * ROWS_PER_CHUNK;

    #pragma unroll 2
    for (int it = 0; it < ROWS_PER_CHUNK / (WAVES * 2); ++it) {
        const int r = row0 + it * (WAVES * 2) + wave * 2 + half;
        const int mk = mask[b * K + r];                       // same addr for 32 lanes -> broadcast
        const size_t rowOff = ((size_t)bh * K + r) * D + l32 * 4;

        float p;
        if (mk != 0) {
            const float4 kv = *reinterpret_cast<const float4*>(key + rowOff);
            float dot = qv.x*kv.x + qv.y*kv.y + qv.z*kv.z + qv.w*kv.w;
            float ksq = kv.x*kv.x + kv.y*kv.y + kv.z*kv.z + kv.w*kv.w;
            #pragma unroll
            for (int s = 16; s >= 1; s >>= 1) {
                dot += __shfl_xor(dot, s, 64);
                ksq += __shfl_xor(ksq, s, 64);
            }
            const float kn = fmaxf(sqrtf(ksq), EPS);
            p = expf(fabsf(dot) / (qn * kn));                 // score in [0,1] -> p in [1,e]
            const float4 vv = *reinterpret_cast<const float4*>(value + rowOff);
            float4 ov;
            ov.x = p * vv.x; ov.y = p * vv.y; ov.z = p * vv.z; ov.w = p * vv.w;
            *reinterpret_cast<float4*>(out + rowOff) = ov;
        } else {
            // exp(-1e9) underflows to +0 in f32; out row is exactly 0.
            p = 0.0f;
            *reinterpret_cast<float4*>(out + rowOff) = make_float4(0.f, 0.f, 0.f, 0.f);
        }
        if (l32 == 0)
            out[P_OFF + (size_t)bh * K + r] = p;
    }
}

extern "C" void kernel_launch(void* const* d_in, const int* in_sizes, int n_in,
                              void* d_out, int out_size, void* d_ws, size_t ws_size,
                              hipStream_t stream) {
    const float* q   = (const float*)d_in[0];
    const float* key = (const float*)d_in[1];
    const float* val = (const float*)d_in[2];
    const int*   msk = (const int*)d_in[3];
    float* out = (float*)d_out;

    dim3 grid(BH * SPLIT);   // 2048 blocks
    dim3 block(WAVES * 64);  // 256 threads
    cosattn_kernel<<<grid, block, 0, stream>>>(q, key, val, msk, out);
}

// Round 2
// 45.442 us; speedup vs baseline: 1.1737x; 1.1737x over previous
//
#include <hip/hip_runtime.h>
#include <math.h>

#define EPS 1e-8f

// Problem shape (fixed by setup_inputs)
constexpr int B = 8, H = 16, K = 2048, D = 128;
constexpr int BH = B * H;
constexpr int SPLIT = 16;                        // K-chunks per (b,h)
constexpr int ROWS_PER_CHUNK = K / SPLIT;        // 128
constexpr int WAVES = 4;                         // 256 threads/block
constexpr int SLOTS = WAVES * 2;                 // 8 half-wave row-slots
constexpr int ROWS_PER_SLOT = ROWS_PER_CHUNK / SLOTS;  // 16
constexpr int GROUP = 4;                         // rows per slot per group
constexpr int NGROUPS = ROWS_PER_SLOT / GROUP;   // 4
constexpr size_t P_OFF = (size_t)BH * K * D;

typedef float f32x4 __attribute__((ext_vector_type(4)));

__global__ __launch_bounds__(256) void cosattn_kernel(
    const float* __restrict__ q,      // [BH, D]
    const float* __restrict__ key,    // [BH, K, D]
    const float* __restrict__ value,  // [BH, K, D]
    const int*   __restrict__ mask,   // [B, K]
    float* __restrict__ out)          // [BH*K*D] ++ [BH*K]
{
    const int tid  = threadIdx.x;
    const int lane = tid & 63;
    const int half = lane >> 5;       // which row of the pair this half-wave owns
    const int l32  = lane & 31;       // lane within 32-lane row group
    const int wave = tid >> 6;
    const int slot = wave * 2 + half; // 0..7

    const int bh    = blockIdx.x / SPLIT;
    const int chunk = blockIdx.x % SPLIT;
    const int b     = bh / H;

    // Per-lane query fragment: q[l32*4 .. l32*4+3] (both halves identical)
    const f32x4 qv = *reinterpret_cast<const f32x4*>(q + (size_t)bh * D + l32 * 4);
    float qsq = qv[0]*qv[0] + qv[1]*qv[1] + qv[2]*qv[2] + qv[3]*qv[3];
    #pragma unroll
    for (int s = 16; s >= 1; s >>= 1)
        qsq += __shfl_xor(qsq, s, 64);   // masks <32: stays inside each half
    const float inv_qn = 1.0f / fmaxf(sqrtf(qsq), EPS);

    const int row0 = chunk * ROWS_PER_CHUNK;

    // --- Hoisted mask bitmap: lanes 0..15 of each half-wave load the masks
    // for this slot's 16 rows; ballot packs them into a 16-bit bitmap.
    int mk = 0;
    if (l32 < ROWS_PER_SLOT)
        mk = mask[b * K + row0 + l32 * SLOTS + slot];
    const unsigned long long bal = __ballot(mk != 0);
    const unsigned bits = (unsigned)(bal >> (half * 32)) & 0xFFFFu;

    const size_t baseRow = (size_t)bh * K;

    #pragma unroll 1
    for (int g = 0; g < NGROUPS; ++g) {
        int   r[GROUP];
        bool  act[GROUP];
        f32x4 kv[GROUP], vv[GROUP];

        // Issue all K and V loads for the group back-to-back (8 in flight).
        #pragma unroll
        for (int j = 0; j < GROUP; ++j) {
            const int i = g * GROUP + j;
            r[j]   = row0 + i * SLOTS + slot;
            act[j] = (bits >> i) & 1u;
            const size_t off = (baseRow + r[j]) * D + l32 * 4;
            kv[j] = act[j] ? *reinterpret_cast<const f32x4*>(key + off)
                           : (f32x4)(0.0f);
            vv[j] = act[j] ? *reinterpret_cast<const f32x4*>(value + off)
                           : (f32x4)(0.0f);
        }

        // Interleaved butterfly reductions for the 4 rows.
        float dot[GROUP], ksq[GROUP];
        #pragma unroll
        for (int j = 0; j < GROUP; ++j) {
            dot[j] = qv[0]*kv[j][0] + qv[1]*kv[j][1] + qv[2]*kv[j][2] + qv[3]*kv[j][3];
            ksq[j] = kv[j][0]*kv[j][0] + kv[j][1]*kv[j][1] + kv[j][2]*kv[j][2] + kv[j][3]*kv[j][3];
        }
        #pragma unroll
        for (int s = 16; s >= 1; s >>= 1) {
            #pragma unroll
            for (int j = 0; j < GROUP; ++j) {
                dot[j] += __shfl_xor(dot[j], s, 64);
                ksq[j] += __shfl_xor(ksq[j], s, 64);
            }
        }

        // Epilogue: p, scaled V row, nontemporal stores.
        #pragma unroll
        for (int j = 0; j < GROUP; ++j) {
            const float kn_inv = 1.0f / fmaxf(sqrtf(ksq[j]), EPS);
            const float p = act[j] ? expf(fabsf(dot[j]) * inv_qn * kn_inv) : 0.0f;
            f32x4 ov;
            ov[0] = p * vv[j][0];
            ov[1] = p * vv[j][1];
            ov[2] = p * vv[j][2];
            ov[3] = p * vv[j][3];
            const size_t off = (baseRow + r[j]) * D + l32 * 4;
            __builtin_nontemporal_store(ov, reinterpret_cast<f32x4*>(out + off));
            if (l32 == 0)
                __builtin_nontemporal_store(p, out + P_OFF + baseRow + r[j]);
        }
    }
}

extern "C" void kernel_launch(void* const* d_in, const int* in_sizes, int n_in,
                              void* d_out, int out_size, void* d_ws, size_t ws_size,
                              hipStream_t stream) {
    const float* q   = (const float*)d_in[0];
    const float* key = (const float*)d_in[1];
    const float* val = (const float*)d_in[2];
    const int*   msk = (const int*)d_in[3];
    float* out = (float*)d_out;

    dim3 grid(BH * SPLIT);   // 2048 blocks
    dim3 block(WAVES * 64);  // 256 threads
    cosattn_kernel<<<grid, block, 0, stream>>>(q, key, val, msk, out);
}